// Round 4
// baseline (1290.455 us; speedup 1.0000x reference)
//
#include <hip/hip_runtime.h>
#include <math.h>

#define HH 1024
#define AA 180
#define NPAIR 90
#define BB 16
#define NCOL (BB*AA)          // 2880 (b,angle) columns
#define RSP 1028              // pair-row stride (float2 entries)
#define GUARD 48              // fallback path: zero guard floats each side
#define RS 1120               // fallback row stride: 48 | 1024 | 48
#define PI_D 3.14159265358979323846

// ws float-offsets
#define OFF_CG   0            // 512 filter coeffs
#define OFF_CST  512          // float4[90]: (c0,c1,s0,s1) pair table
#define OFF_CST2 872          // float2[180]: (c,s) fallback table
#define OFF_DATA 1232         // pair rows (float2[NCOL*RSP]) or fallback xaf

typedef float f2 __attribute__((ext_vector_type(2)));

__device__ __forceinline__ float fractf_(float x) {
#if __has_builtin(__builtin_amdgcn_fractf)
    return __builtin_amdgcn_fractf(x);   // v_fract_f32: x - floor(x)
#else
    return x - floorf(x);
#endif
}

// ---------------- tables ----------------
__global__ __launch_bounds__(512) void k_tables(float* __restrict__ ws) {
    int t = threadIdx.x;
    if (t < 512) {
        double d = 2.0 * t + 1.0;
        ws[OFF_CG + t] = (float)(-2.0 / (PI_D * PI_D * d * d));
    }
    if (t < AA) {
        float thf = (float)t * 0.017453292519943295f;  // fp32(pi/180)
        double th = (double)thf;
        float2* cst2 = (float2*)(ws + OFF_CST2);
        cst2[t] = make_float2((float)(512.0 * cos(th)), (float)(512.0 * sin(th)));
    }
    if (t < NPAIR) {
        float t0 = (float)(2*t)     * 0.017453292519943295f;
        float t1 = (float)(2*t + 1) * 0.017453292519943295f;
        float4* cst4 = (float4*)(ws + OFF_CST);
        cst4[t] = make_float4((float)(512.0 * cos((double)t0)),
                              (float)(512.0 * cos((double)t1)),
                              (float)(512.0 * sin((double)t0)),
                              (float)(512.0 * sin((double)t1)));
    }
}

// ---------------- shared conv core (fused angle-interp + ramp filter) ----------------
// Computes acc[16] = filtered values y[16t..16t+15] for column `col`.
__device__ __forceinline__ void filter_core(const float* __restrict__ x,
                                            const float* __restrict__ cg,
                                            float* xsp, int t, int col,
                                            float acc[16]) {
    int b = col / AA, a = col - b * AA;

    float4* z4 = (float4*)xsp;
    #pragma unroll
    for (int i = t; i < 816; i += 64) z4[i] = make_float4(0.f, 0.f, 0.f, 0.f);
    __syncthreads();

    // angle interp weights (matches reference _backproject's xa)
    float ixf = (float)a * (float)(180.0/179.0) - 0.5f;
    float fl = floorf(ixf);
    int i0 = (int)fl;
    float fx = ixf - fl;
    float w0 = (i0 >= 0)      ? (1.0f - fx) : 0.0f;
    float w1 = (i0 + 1 < AA)  ? fx          : 0.0f;
    int c0 = max(i0, 0);
    int c1 = min(i0 + 1, AA - 1);
    const float* xb = x + (size_t)b * HH * AA;
    for (int i = t; i < HH; i += 64) {
        float v = w0 * xb[i * AA + c0] + w1 * xb[i * AA + c1];
        int q = 1024 + i;
        xsp[q + (q >> 4)] = v;         // lane stride 17 -> conflict-free
    }
    __syncthreads();

    int pp = 17 * t;                   // swizzled base of this thread's p=16t
    float Lw[16], Rw[16];
    #pragma unroll
    for (int m = 0; m < 16; ++m) {
        int f = 1024 + m;
        acc[m] = 0.5f * xsp[pp + f + (f >> 4)];
    }
    #pragma unroll
    for (int m = 0; m < 16; ++m) {
        int f = 1 + m;                 // x[p+m-1023]
        Lw[(m + 1) & 15] = xsp[pp + f + (f >> 4)];
        int g = 2047 + m;              // x[p+m+1023]
        Rw[(m - 1) & 15] = xsp[pp + g + (g >> 4)];
    }

    for (int it0 = 0; it0 < 512; it0 += 8) {
        #pragma unroll
        for (int u = 0; u < 8; ++u) {
            int it = it0 + u;          // d = 1023 - 2*it
            float cv = cg[511 - it];   // uniform -> s_load
            #pragma unroll
            for (int m = 0; m < 16; ++m) {
                acc[m] = fmaf(cv, Lw[(m + 2*u + 1) & 15] + Rw[(m - 2*u - 1) & 15], acc[m]);
            }
            int fL  = 2*it + 17;
            Lw[(2*u + 1) & 15] = xsp[pp + fL  + (fL  >> 4)];
            int fL2 = 2*it + 18;
            Lw[(2*u + 2) & 15] = xsp[pp + fL2 + (fL2 >> 4)];
            int fR  = 2045 - 2*it;
            Rw[(13 - 2*u) & 15] = xsp[pp + fR  + (fR  >> 4)];
            int fR2 = 2046 - 2*it;
            Rw[(14 - 2*u) & 15] = xsp[pp + fR2 + (fR2 >> 4)];
        }
    }
}

// ---------------- pair-output filter ----------------
// Row layout: float2 pair[RSP]; pair[s] = (y[s-2], y[s-1]) * SC, y zero outside [0,1023].
// Written range s in [0,1026]; bproj index j = trunc(iy + 513.5-511.5... see bproj).
__global__ __launch_bounds__(64) void k_filter_pair(const float* __restrict__ x,
                                                    const float* __restrict__ cg,
                                                    float2* __restrict__ pair) {
    __shared__ float xsp[3264];
    int t = threadIdx.x;
    int col = blockIdx.x;
    float acc[16];
    filter_core(x, cg, xsp, t, col, acc);

    const float SC = (float)(PI_D / 360.0);
    float yv[16];
    #pragma unroll
    for (int m = 0; m < 16; ++m) yv[m] = acc[m] * SC;
    float ynext = __shfl_down(yv[0], 1);   // lane t gets lane t+1's y[16(t+1)]
    if (t == 63) ynext = 0.f;              // y[1024] = 0

    float2* rowp = pair + (size_t)col * RSP;
    int s0 = 16 * t + 2;                   // pair k=16t -> storage s=k+2
    #pragma unroll
    for (int m = 0; m < 15; ++m) rowp[s0 + m] = make_float2(yv[m], yv[m + 1]);
    rowp[s0 + 15] = make_float2(yv[15], ynext);
    if (t == 0) {
        rowp[0] = make_float2(0.f, 0.f);       // (y[-2], y[-1])
        rowp[1] = make_float2(0.f, yv[0]);     // (y[-1], y[0])
    }
    if (t == 63) rowp[1026] = make_float2(0.f, 0.f);  // (y[1024], y[1025])
}

// ---------------- pair backprojection: 1 px/thread, 2 angles/iter ----------------
__global__ __launch_bounds__(256, 8) void k_bproj_pair(const float* __restrict__ ws,
                                                       const float2* __restrict__ pair,
                                                       float* __restrict__ out) {
    const float4* cst4 = (const float4*)(ws + OFF_CST);
    int t = threadIdx.x;
    int tx = t & 15, ty = t >> 4;
    int bx = blockIdx.x, by = blockIdx.y, b = blockIdx.z;
    int xg = bx * 16 + tx, yg = by * 16 + ty;
    const float DEL = (float)(2.0 / 1023.0);
    // bit-exact jnp.linspace replication (mul then add, no contraction)
    float ux = __fadd_rn(__fmul_rn((float)xg, DEL), -1.0f);
    float uy = __fadd_rn(__fmul_rn((float)yg, DEL), -1.0f);

    size_t oidx = ((size_t)b << 20) + ((size_t)yg << 10) + (size_t)xg;

    // per-wave 16x4 strip early exit (uniform within wave)
    {
        int w4 = (t >> 6) << 2;            // first row of this wave's strip
        float cx0 = __fadd_rn(__fmul_rn((float)(bx*16),      DEL), -1.0f);
        float cx1 = __fadd_rn(__fmul_rn((float)(bx*16 + 15), DEL), -1.0f);
        float sy0 = __fadd_rn(__fmul_rn((float)(by*16 + w4),     DEL), -1.0f);
        float sy1 = __fadd_rn(__fmul_rn((float)(by*16 + w4 + 3), DEL), -1.0f);
        float minax = (cx0 <= 0.f && cx1 >= 0.f) ? 0.f : fminf(fabsf(cx0), fabsf(cx1));
        float minay = (sy0 <= 0.f && sy1 >= 0.f) ? 0.f : fminf(fabsf(sy0), fabsf(sy1));
        if (minax * minax + minay * minay > 1.000001f) { out[oidx] = 0.f; return; }
    }

    // bit-exact circle mask decides inside; outside lanes get coords zeroed so
    // their (masked) loads stay at index 513 — all reads in [0,1026].
    float r2 = __fadd_rn(__fmul_rn(ux, ux), __fmul_rn(uy, uy));
    bool inside = (r2 <= 1.0f);
    float uxe  = inside ? ux  : 0.f;
    float nuye = inside ? -uy : 0.f;
    f2 ux2  = {uxe, uxe};
    f2 nuy2 = {nuye, nuye};
    f2 B2   = {513.5f, 513.5f};           // 511.5 + 2 (pair-entry shift)

    const float2* rA = pair + (size_t)b * (AA * RSP);       // angle 2p
    const float2* rB = rA + RSP;                             // angle 2p+1
    float acc0 = 0.f, acc1 = 0.f;

    #pragma unroll 3
    for (int p = 0; p < NPAIR; ++p) {
        float4 cs = cst4[p];               // uniform -> s_load_dwordx4 (c0,c1,s0,s1)
        f2 cc = {cs.x, cs.y};
        f2 ss = {cs.z, cs.w};
        f2 P = __builtin_elementwise_fma(ux2, cc,
               __builtin_elementwise_fma(nuy2, ss, B2));     // v_pk_fma_f32 x2
        int j0 = (int)P.x, j1 = (int)P.y;  // trunc == floor (P >= 1.4)
        float fy0 = fractf_(P.x);
        float fy1 = fractf_(P.y);
        float2 v0 = rA[j0];                // one dwordx2 gather = both taps
        float2 v1 = rB[j1];
        acc0 = fmaf(fy0, v0.y - v0.x, acc0 + v0.x);
        acc1 = fmaf(fy1, v1.y - v1.x, acc1 + v1.x);
        rA += 2 * RSP; rB += 2 * RSP;
    }

    out[oidx] = inside ? (acc0 + acc1) : 0.f;
}

// ================= fallback path (R3, proven) — used if ws too small ==========
__global__ __launch_bounds__(64) void k_filter_sc(const float* __restrict__ x,
                                                  const float* __restrict__ cg,
                                                  float* __restrict__ xaf) {
    __shared__ float xsp[3264];
    int t = threadIdx.x;
    int col = blockIdx.x;
    float acc[16];
    filter_core(x, cg, xsp, t, col, acc);

    const float SC = (float)(PI_D / 360.0);
    float* rb = xaf + (size_t)col * RS;
    if (t < 12)            ((float4*)rb)[t]              = make_float4(0.f,0.f,0.f,0.f);
    else if (t < 24)       ((float4*)rb)[268 + (t - 12)] = make_float4(0.f,0.f,0.f,0.f);
    float4* o4 = (float4*)(rb + GUARD + 16 * t);
    #pragma unroll
    for (int m4 = 0; m4 < 4; ++m4)
        o4[m4] = make_float4(acc[4*m4]*SC, acc[4*m4+1]*SC, acc[4*m4+2]*SC, acc[4*m4+3]*SC);
}

__global__ __launch_bounds__(256, 4) void k_bproj_sc(const float* __restrict__ ws,
                                                     const float* __restrict__ xaf,
                                                     float* __restrict__ out) {
    const float2* cst2 = (const float2*)(ws + OFF_CST2);
    int t = threadIdx.x;
    int tx = t & 15, ty = t >> 4;
    int bx = blockIdx.x, by = blockIdx.y, b = blockIdx.z;
    int xg = bx * 16 + tx, yg = by * 16 + ty;
    const float DEL = (float)(2.0 / 1023.0);
    float ux = __fadd_rn(__fmul_rn((float)xg, DEL), -1.0f);
    float uy = __fadd_rn(__fmul_rn((float)yg, DEL), -1.0f);

    float cx0 = __fadd_rn(__fmul_rn((float)(bx*16),      DEL), -1.0f);
    float cx1 = __fadd_rn(__fmul_rn((float)(bx*16 + 15), DEL), -1.0f);
    float cy0 = __fadd_rn(__fmul_rn((float)(by*16),      DEL), -1.0f);
    float cy1 = __fadd_rn(__fmul_rn((float)(by*16 + 15), DEL), -1.0f);
    float minax = (cx0 <= 0.f && cx1 >= 0.f) ? 0.f : fminf(fabsf(cx0), fabsf(cx1));
    float minay = (cy0 <= 0.f && cy1 >= 0.f) ? 0.f : fminf(fabsf(cy0), fabsf(cy1));
    float rmin2 = minax * minax + minay * minay;

    size_t oidx = ((size_t)b << 20) + ((size_t)yg << 10) + (size_t)xg;
    if (rmin2 > 1.000001f) { out[oidx] = 0.f; return; }

    const float* row = xaf + (size_t)b * (AA * RS);
    const float BIAS = 511.5f + (float)GUARD;
    float nuy = -uy;
    float acc = 0.f;

    #pragma unroll 4
    for (int a = 0; a < AA; ++a) {
        float2 cs = cst2[a];
        float iy = fmaf(ux, cs.x, fmaf(nuy, cs.y, BIAS));
        int j = (int)iy;
        float fy = fractf_(iy);
        float v0 = row[j];
        float v1 = row[j + 1];
        acc = fmaf(fy, v1 - v0, acc + v0);
        row += RS;
    }

    float r2 = __fadd_rn(__fmul_rn(ux, ux), __fmul_rn(uy, uy));
    out[oidx] = (r2 <= 1.0f) ? acc : 0.f;
}

extern "C" void kernel_launch(void* const* d_in, const int* in_sizes, int n_in,
                              void* d_out, int out_size, void* d_ws, size_t ws_size,
                              hipStream_t stream) {
    const float* x = (const float*)d_in[0];
    float* out = (float*)d_out;
    float* ws = (float*)d_ws;
    float* cg  = ws + OFF_CG;

    hipLaunchKernelGGL(k_tables, dim3(1), dim3(512), 0, stream, ws);

    size_t need_pair = (size_t)OFF_DATA * 4 + (size_t)NCOL * RSP * sizeof(float2);
    if (ws_size >= need_pair) {
        float2* pair = (float2*)(ws + OFF_DATA);
        hipLaunchKernelGGL(k_filter_pair, dim3(NCOL), dim3(64), 0, stream, x, cg, pair);
        hipLaunchKernelGGL(k_bproj_pair, dim3(64, 64, BB), dim3(256), 0, stream, ws, pair, out);
    } else {
        float* xaf = ws + OFF_DATA;
        hipLaunchKernelGGL(k_filter_sc, dim3(NCOL), dim3(64), 0, stream, x, cg, xaf);
        hipLaunchKernelGGL(k_bproj_sc, dim3(64, 64, BB), dim3(256), 0, stream, ws, xaf, out);
    }
}

// Round 5
// 1244.824 us; speedup vs baseline: 1.0367x; 1.0367x over previous
//
#include <hip/hip_runtime.h>
#include <math.h>

#define HH 1024
#define AA 180
#define BB 16
#define NCOL (BB*AA)          // 2880 (b,angle) columns
#define RSP 1028              // pair-row stride (float2 entries)
#define GUARD 48              // fallback path: zero guard floats each side
#define RS 1120               // fallback row stride
#define PI_D 3.14159265358979323846

// ws float-offsets
#define OFF_CG   0            // 512 filter coeffs
#define OFF_CST  512          // float4[180]: (512c, 512s, D4=-4*DEL*512s, 0)
#define OFF_CST2 1232         // float2[180]: (c,s) fallback table
#define OFF_DATA 1600         // pair rows (float2[NCOL*RSP]) or fallback xaf

__device__ __forceinline__ float fractf_(float x) {
#if __has_builtin(__builtin_amdgcn_fractf)
    return __builtin_amdgcn_fractf(x);   // v_fract_f32
#else
    return x - floorf(x);
#endif
}

// ---------------- tables ----------------
__global__ __launch_bounds__(512) void k_tables(float* __restrict__ ws) {
    int t = threadIdx.x;
    if (t < 512) {
        double d = 2.0 * t + 1.0;
        ws[OFF_CG + t] = (float)(-2.0 / (PI_D * PI_D * d * d));
    }
    if (t < AA) {
        float thf = (float)t * 0.017453292519943295f;  // fp32(pi/180)
        double th = (double)thf;
        double c = cos(th), s = sin(th);
        float4* cst4 = (float4*)(ws + OFF_CST);
        // D4 = d(iy)/d(k) for y-step of 4 pixels: -4*DEL*512*s
        cst4[t] = make_float4((float)(512.0 * c), (float)(512.0 * s),
                              (float)(-(4096.0 / 1023.0) * s), 0.f);
        float2* cst2 = (float2*)(ws + OFF_CST2);
        cst2[t] = make_float2((float)(512.0 * c), (float)(512.0 * s));
    }
}

// ---------------- shared conv core (fused angle-interp + ramp filter) ----------------
__device__ __forceinline__ void filter_core(const float* __restrict__ x,
                                            const float* __restrict__ cg,
                                            float* xsp, int t, int col,
                                            float acc[16]) {
    int b = col / AA, a = col - b * AA;

    float4* z4 = (float4*)xsp;
    #pragma unroll
    for (int i = t; i < 816; i += 64) z4[i] = make_float4(0.f, 0.f, 0.f, 0.f);
    __syncthreads();

    float ixf = (float)a * (float)(180.0/179.0) - 0.5f;
    float fl = floorf(ixf);
    int i0 = (int)fl;
    float fx = ixf - fl;
    float w0 = (i0 >= 0)      ? (1.0f - fx) : 0.0f;
    float w1 = (i0 + 1 < AA)  ? fx          : 0.0f;
    int c0 = max(i0, 0);
    int c1 = min(i0 + 1, AA - 1);
    const float* xb = x + (size_t)b * HH * AA;
    for (int i = t; i < HH; i += 64) {
        float v = w0 * xb[i * AA + c0] + w1 * xb[i * AA + c1];
        int q = 1024 + i;
        xsp[q + (q >> 4)] = v;         // lane stride 17 -> conflict-free
    }
    __syncthreads();

    int pp = 17 * t;
    float Lw[16], Rw[16];
    #pragma unroll
    for (int m = 0; m < 16; ++m) {
        int f = 1024 + m;
        acc[m] = 0.5f * xsp[pp + f + (f >> 4)];
    }
    #pragma unroll
    for (int m = 0; m < 16; ++m) {
        int f = 1 + m;
        Lw[(m + 1) & 15] = xsp[pp + f + (f >> 4)];
        int g = 2047 + m;
        Rw[(m - 1) & 15] = xsp[pp + g + (g >> 4)];
    }

    for (int it0 = 0; it0 < 512; it0 += 8) {
        #pragma unroll
        for (int u = 0; u < 8; ++u) {
            int it = it0 + u;
            float cv = cg[511 - it];
            #pragma unroll
            for (int m = 0; m < 16; ++m) {
                acc[m] = fmaf(cv, Lw[(m + 2*u + 1) & 15] + Rw[(m - 2*u - 1) & 15], acc[m]);
            }
            int fL  = 2*it + 17;
            Lw[(2*u + 1) & 15] = xsp[pp + fL  + (fL  >> 4)];
            int fL2 = 2*it + 18;
            Lw[(2*u + 2) & 15] = xsp[pp + fL2 + (fL2 >> 4)];
            int fR  = 2045 - 2*it;
            Rw[(13 - 2*u) & 15] = xsp[pp + fR  + (fR  >> 4)];
            int fR2 = 2046 - 2*it;
            Rw[(14 - 2*u) & 15] = xsp[pp + fR2 + (fR2 >> 4)];
        }
    }
}

// ---------------- pair-output filter ----------------
// pair[s] = (y[s-2], y[s-1]) * SC, zero outside; valid s in [0,1026].
__global__ __launch_bounds__(64) void k_filter_pair(const float* __restrict__ x,
                                                    const float* __restrict__ cg,
                                                    float2* __restrict__ pair) {
    __shared__ float xsp[3264];
    int t = threadIdx.x;
    int col = blockIdx.x;
    float acc[16];
    filter_core(x, cg, xsp, t, col, acc);

    const float SC = (float)(PI_D / 360.0);
    float yv[16];
    #pragma unroll
    for (int m = 0; m < 16; ++m) yv[m] = acc[m] * SC;
    float ynext = __shfl_down(yv[0], 1);
    if (t == 63) ynext = 0.f;

    float2* rowp = pair + (size_t)col * RSP;
    int s0 = 16 * t + 2;
    #pragma unroll
    for (int m = 0; m < 15; ++m) rowp[s0 + m] = make_float2(yv[m], yv[m + 1]);
    rowp[s0 + 15] = make_float2(yv[15], ynext);
    if (t == 0) {
        rowp[0] = make_float2(0.f, 0.f);
        rowp[1] = make_float2(0.f, yv[0]);
    }
    if (t == 63) rowp[1026] = make_float2(0.f, 0.f);
}

// ---------------- backprojection: 4 y-px/thread, 2 angles/iter, 8 loads in flight ----
template<bool CLAMP>
__device__ __forceinline__ void bp_loop(const float4* __restrict__ cst,
                                        const float2* __restrict__ r,
                                        float ux, float nuy,
                                        float& a0, float& a1, float& a2, float& a3) {
    #pragma unroll 1
    for (int p = 0; p < AA/2; ++p) {
        float4 cA = cst[2*p];               // uniform -> s_load_dwordx4
        float4 cB = cst[2*p + 1];
        const float2* rA = r;
        const float2* rB = r + RSP;
        float iA0 = fmaf(ux, cA.x, fmaf(nuy, cA.y, 513.5f));
        float iA1 = iA0 + cA.z;
        float iA2 = fmaf(2.0f, cA.z, iA0);
        float iA3 = iA2 + cA.z;
        float iB0 = fmaf(ux, cB.x, fmaf(nuy, cB.y, 513.5f));
        float iB1 = iB0 + cB.z;
        float iB2 = fmaf(2.0f, cB.z, iB0);
        float iB3 = iB2 + cB.z;
        int jA0 = (int)iA0, jA1 = (int)iA1, jA2 = (int)iA2, jA3 = (int)iA3;
        int jB0 = (int)iB0, jB1 = (int)iB1, jB2 = (int)iB2, jB3 = (int)iB3;
        if (CLAMP) {
            jA0 = min(max(jA0, 0), 1026); jA1 = min(max(jA1, 0), 1026);
            jA2 = min(max(jA2, 0), 1026); jA3 = min(max(jA3, 0), 1026);
            jB0 = min(max(jB0, 0), 1026); jB1 = min(max(jB1, 0), 1026);
            jB2 = min(max(jB2, 0), 1026); jB3 = min(max(jB3, 0), 1026);
        }
        // 8 independent dwordx2 gathers
        float2 vA0 = rA[jA0], vA1 = rA[jA1], vA2 = rA[jA2], vA3 = rA[jA3];
        float2 vB0 = rB[jB0], vB1 = rB[jB1], vB2 = rB[jB2], vB3 = rB[jB3];
        float fA0 = fractf_(iA0), fA1 = fractf_(iA1), fA2 = fractf_(iA2), fA3 = fractf_(iA3);
        float fB0 = fractf_(iB0), fB1 = fractf_(iB1), fB2 = fractf_(iB2), fB3 = fractf_(iB3);
        a0 = fmaf(fA0, vA0.y - vA0.x, a0 + vA0.x);
        a1 = fmaf(fA1, vA1.y - vA1.x, a1 + vA1.x);
        a2 = fmaf(fA2, vA2.y - vA2.x, a2 + vA2.x);
        a3 = fmaf(fA3, vA3.y - vA3.x, a3 + vA3.x);
        a0 = fmaf(fB0, vB0.y - vB0.x, a0 + vB0.x);
        a1 = fmaf(fB1, vB1.y - vB1.x, a1 + vB1.x);
        a2 = fmaf(fB2, vB2.y - vB2.x, a2 + vB2.x);
        a3 = fmaf(fB3, vB3.y - vB3.x, a3 + vB3.x);
        r += 2 * RSP;
    }
}

__global__ __launch_bounds__(256, 4) void k_bproj4(const float* __restrict__ ws,
                                                   const float2* __restrict__ pair,
                                                   float* __restrict__ out) {
    const float4* cst = (const float4*)(ws + OFF_CST);
    int t = threadIdx.x;
    int n = blockIdx.x;
    // XCD-batch swizzle: blocks ≡ i (mod 8) handle batches {i, i+8} -> per-XCD
    // working set = 2 slabs (~3 MB) -> L2-resident. Heuristic only.
    int b    = (n & 7) + 8 * ((n >> 3) & 1);
    int tile = n >> 4;                  // [0,1024)
    int bx = tile & 63;                 // x-tile (16 px)
    int by = tile >> 6;                 // y-tile (64 px)
    int tx = t & 15;
    int tl = (t >> 4) & 3;
    int w  = t >> 6;
    int xg = bx * 16 + tx;
    int ys = by * 64 + w * 16;          // wave strip: rows [ys, ys+16)
    int yg = ys + tl;                   // pixel k at yg + 4k

    const float DEL = (float)(2.0 / 1023.0);
    float ux  = __fadd_rn(__fmul_rn((float)xg, DEL), -1.0f);
    float uy0 = __fadd_rn(__fmul_rn((float)yg,        DEL), -1.0f);
    float uy1 = __fadd_rn(__fmul_rn((float)(yg + 4),  DEL), -1.0f);
    float uy2 = __fadd_rn(__fmul_rn((float)(yg + 8),  DEL), -1.0f);
    float uy3 = __fadd_rn(__fmul_rn((float)(yg + 12), DEL), -1.0f);

    // strip classification (16x16, wave-uniform)
    float cx0 = __fadd_rn(__fmul_rn((float)(bx*16),      DEL), -1.0f);
    float cx1 = __fadd_rn(__fmul_rn((float)(bx*16 + 15), DEL), -1.0f);
    float sy0 = __fadd_rn(__fmul_rn((float)ys,           DEL), -1.0f);
    float sy1 = __fadd_rn(__fmul_rn((float)(ys + 15),    DEL), -1.0f);
    float minax = (cx0 <= 0.f && cx1 >= 0.f) ? 0.f : fminf(fabsf(cx0), fabsf(cx1));
    float minay = (sy0 <= 0.f && sy1 >= 0.f) ? 0.f : fminf(fabsf(sy0), fabsf(sy1));
    float rmin2 = minax * minax + minay * minay;
    float maxax = fmaxf(fabsf(cx0), fabsf(cx1));
    float maxay = fmaxf(fabsf(sy0), fabsf(sy1));
    float rmax2 = maxax * maxax + maxay * maxay;

    size_t o0 = ((size_t)b << 20) + ((size_t)yg << 10) + (size_t)xg;
    float* p0 = out + o0;

    if (rmin2 > 1.000001f) {            // strip fully outside
        p0[0] = 0.f; p0[4 << 10] = 0.f; p0[8 << 10] = 0.f; p0[12 << 10] = 0.f;
        return;
    }

    const float2* r = pair + (size_t)b * (AA * RSP);
    float nuy = -uy0;
    float a0 = 0.f, a1 = 0.f, a2 = 0.f, a3 = 0.f;

    if (rmax2 <= 0.9999f) {
        // fast path: every pixel strictly inside; j in [1,1025] guaranteed
        bp_loop<false>(cst, r, ux, nuy, a0, a1, a2, a3);
        p0[0] = a0; p0[4 << 10] = a1; p0[8 << 10] = a2; p0[12 << 10] = a3;
    } else {
        bp_loop<true>(cst, r, ux, nuy, a0, a1, a2, a3);
        // bit-exact circle mask per pixel
        float xx = __fmul_rn(ux, ux);
        float r20 = __fadd_rn(xx, __fmul_rn(uy0, uy0));
        float r21 = __fadd_rn(xx, __fmul_rn(uy1, uy1));
        float r22 = __fadd_rn(xx, __fmul_rn(uy2, uy2));
        float r23 = __fadd_rn(xx, __fmul_rn(uy3, uy3));
        p0[0]       = (r20 <= 1.0f) ? a0 : 0.f;
        p0[4 << 10] = (r21 <= 1.0f) ? a1 : 0.f;
        p0[8 << 10] = (r22 <= 1.0f) ? a2 : 0.f;
        p0[12 << 10] = (r23 <= 1.0f) ? a3 : 0.f;
    }
}

// ================= fallback path (R3, proven) — used if ws too small ==========
__global__ __launch_bounds__(64) void k_filter_sc(const float* __restrict__ x,
                                                  const float* __restrict__ cg,
                                                  float* __restrict__ xaf) {
    __shared__ float xsp[3264];
    int t = threadIdx.x;
    int col = blockIdx.x;
    float acc[16];
    filter_core(x, cg, xsp, t, col, acc);

    const float SC = (float)(PI_D / 360.0);
    float* rb = xaf + (size_t)col * RS;
    if (t < 12)            ((float4*)rb)[t]              = make_float4(0.f,0.f,0.f,0.f);
    else if (t < 24)       ((float4*)rb)[268 + (t - 12)] = make_float4(0.f,0.f,0.f,0.f);
    float4* o4 = (float4*)(rb + GUARD + 16 * t);
    #pragma unroll
    for (int m4 = 0; m4 < 4; ++m4)
        o4[m4] = make_float4(acc[4*m4]*SC, acc[4*m4+1]*SC, acc[4*m4+2]*SC, acc[4*m4+3]*SC);
}

__global__ __launch_bounds__(256, 4) void k_bproj_sc(const float* __restrict__ ws,
                                                     const float* __restrict__ xaf,
                                                     float* __restrict__ out) {
    const float2* cst2 = (const float2*)(ws + OFF_CST2);
    int t = threadIdx.x;
    int tx = t & 15, ty = t >> 4;
    int bx = blockIdx.x, by = blockIdx.y, b = blockIdx.z;
    int xg = bx * 16 + tx, yg = by * 16 + ty;
    const float DEL = (float)(2.0 / 1023.0);
    float ux = __fadd_rn(__fmul_rn((float)xg, DEL), -1.0f);
    float uy = __fadd_rn(__fmul_rn((float)yg, DEL), -1.0f);

    float cx0 = __fadd_rn(__fmul_rn((float)(bx*16),      DEL), -1.0f);
    float cx1 = __fadd_rn(__fmul_rn((float)(bx*16 + 15), DEL), -1.0f);
    float cy0 = __fadd_rn(__fmul_rn((float)(by*16),      DEL), -1.0f);
    float cy1 = __fadd_rn(__fmul_rn((float)(by*16 + 15), DEL), -1.0f);
    float minax = (cx0 <= 0.f && cx1 >= 0.f) ? 0.f : fminf(fabsf(cx0), fabsf(cx1));
    float minay = (cy0 <= 0.f && cy1 >= 0.f) ? 0.f : fminf(fabsf(cy0), fabsf(cy1));
    float rmin2 = minax * minax + minay * minay;

    size_t oidx = ((size_t)b << 20) + ((size_t)yg << 10) + (size_t)xg;
    if (rmin2 > 1.000001f) { out[oidx] = 0.f; return; }

    const float* row = xaf + (size_t)b * (AA * RS);
    const float BIAS = 511.5f + (float)GUARD;
    float nuy = -uy;
    float acc = 0.f;

    #pragma unroll 4
    for (int a = 0; a < AA; ++a) {
        float2 cs = cst2[a];
        float iy = fmaf(ux, cs.x, fmaf(nuy, cs.y, BIAS));
        int j = (int)iy;
        float fy = fractf_(iy);
        float v0 = row[j];
        float v1 = row[j + 1];
        acc = fmaf(fy, v1 - v0, acc + v0);
        row += RS;
    }

    float r2 = __fadd_rn(__fmul_rn(ux, ux), __fmul_rn(uy, uy));
    out[oidx] = (r2 <= 1.0f) ? acc : 0.f;
}

extern "C" void kernel_launch(void* const* d_in, const int* in_sizes, int n_in,
                              void* d_out, int out_size, void* d_ws, size_t ws_size,
                              hipStream_t stream) {
    const float* x = (const float*)d_in[0];
    float* out = (float*)d_out;
    float* ws = (float*)d_ws;
    float* cg  = ws + OFF_CG;

    hipLaunchKernelGGL(k_tables, dim3(1), dim3(512), 0, stream, ws);

    size_t need_pair = (size_t)OFF_DATA * 4 + (size_t)NCOL * RSP * sizeof(float2);
    if (ws_size >= need_pair) {
        float2* pair = (float2*)(ws + OFF_DATA);
        hipLaunchKernelGGL(k_filter_pair, dim3(NCOL), dim3(64), 0, stream, x, cg, pair);
        hipLaunchKernelGGL(k_bproj4, dim3(16384), dim3(256), 0, stream, ws, pair, out);
    } else {
        float* xaf = ws + OFF_DATA;
        hipLaunchKernelGGL(k_filter_sc, dim3(NCOL), dim3(64), 0, stream, x, cg, xaf);
        hipLaunchKernelGGL(k_bproj_sc, dim3(64, 64, BB), dim3(256), 0, stream, ws, xaf, out);
    }
}

// Round 6
// 648.000 us; speedup vs baseline: 1.9914x; 1.9210x over previous
//
#include <hip/hip_runtime.h>
#include <math.h>

#define HH 1024
#define AA 180
#define BB 16
#define NCOL (BB*AA)          // 2880 (b,angle) columns
#define RSP 1028              // pair-row stride (float2 entries)
#define GUARD 48              // fallback path: zero guard floats each side
#define RS 1120               // fallback row stride
#define PI_D 3.14159265358979323846

#define GANG 45               // angles staged per group (180 = 4*45)
#define WIN 48                // window entries (float2) per angle

// ws float-offsets
#define OFF_CG   0            // 512 filter coeffs
#define OFF_CST  512          // float4[180]: (512c, 512s, D8=-8*DEL*512*s, 0)
#define OFF_CST2 1232         // float2[180]: (c,s) fallback table
#define OFF_DATA 1600         // pair rows (float2[NCOL*RSP]) or fallback xaf

__device__ __forceinline__ float fractf_(float x) {
#if __has_builtin(__builtin_amdgcn_fractf)
    return __builtin_amdgcn_fractf(x);   // v_fract_f32
#else
    return x - floorf(x);
#endif
}

// ---------------- tables ----------------
__global__ __launch_bounds__(512) void k_tables(float* __restrict__ ws) {
    int t = threadIdx.x;
    if (t < 512) {
        double d = 2.0 * t + 1.0;
        ws[OFF_CG + t] = (float)(-2.0 / (PI_D * PI_D * d * d));
    }
    if (t < AA) {
        float thf = (float)t * 0.017453292519943295f;  // fp32(pi/180)
        double th = (double)thf;
        double c = cos(th), s = sin(th);
        float4* cst4 = (float4*)(ws + OFF_CST);
        // D8 = d(iy)/d(k) for y-step of 8 pixels: -8*DEL*512*s = -(8192/1023)*s
        cst4[t] = make_float4((float)(512.0 * c), (float)(512.0 * s),
                              (float)(-(8192.0 / 1023.0) * s), 0.f);
        float2* cst2 = (float2*)(ws + OFF_CST2);
        cst2[t] = make_float2((float)(512.0 * c), (float)(512.0 * s));
    }
}

// ---------------- shared conv core (fused angle-interp + ramp filter) ----------------
__device__ __forceinline__ void filter_core(const float* __restrict__ x,
                                            const float* __restrict__ cg,
                                            float* xsp, int t, int col,
                                            float acc[16]) {
    int b = col / AA, a = col - b * AA;

    float4* z4 = (float4*)xsp;
    #pragma unroll
    for (int i = t; i < 816; i += 64) z4[i] = make_float4(0.f, 0.f, 0.f, 0.f);
    __syncthreads();

    float ixf = (float)a * (float)(180.0/179.0) - 0.5f;
    float fl = floorf(ixf);
    int i0 = (int)fl;
    float fx = ixf - fl;
    float w0 = (i0 >= 0)      ? (1.0f - fx) : 0.0f;
    float w1 = (i0 + 1 < AA)  ? fx          : 0.0f;
    int c0 = max(i0, 0);
    int c1 = min(i0 + 1, AA - 1);
    const float* xb = x + (size_t)b * HH * AA;
    for (int i = t; i < HH; i += 64) {
        float v = w0 * xb[i * AA + c0] + w1 * xb[i * AA + c1];
        int q = 1024 + i;
        xsp[q + (q >> 4)] = v;         // lane stride 17 -> conflict-free
    }
    __syncthreads();

    int pp = 17 * t;
    float Lw[16], Rw[16];
    #pragma unroll
    for (int m = 0; m < 16; ++m) {
        int f = 1024 + m;
        acc[m] = 0.5f * xsp[pp + f + (f >> 4)];
    }
    #pragma unroll
    for (int m = 0; m < 16; ++m) {
        int f = 1 + m;
        Lw[(m + 1) & 15] = xsp[pp + f + (f >> 4)];
        int g = 2047 + m;
        Rw[(m - 1) & 15] = xsp[pp + g + (g >> 4)];
    }

    for (int it0 = 0; it0 < 512; it0 += 8) {
        #pragma unroll
        for (int u = 0; u < 8; ++u) {
            int it = it0 + u;
            float cv = cg[511 - it];
            #pragma unroll
            for (int m = 0; m < 16; ++m) {
                acc[m] = fmaf(cv, Lw[(m + 2*u + 1) & 15] + Rw[(m - 2*u - 1) & 15], acc[m]);
            }
            int fL  = 2*it + 17;
            Lw[(2*u + 1) & 15] = xsp[pp + fL  + (fL  >> 4)];
            int fL2 = 2*it + 18;
            Lw[(2*u + 2) & 15] = xsp[pp + fL2 + (fL2 >> 4)];
            int fR  = 2045 - 2*it;
            Rw[(13 - 2*u) & 15] = xsp[pp + fR  + (fR  >> 4)];
            int fR2 = 2046 - 2*it;
            Rw[(14 - 2*u) & 15] = xsp[pp + fR2 + (fR2 >> 4)];
        }
    }
}

// ---------------- pair-output filter ----------------
// pair[s] = (y[s-2], y[s-1]) * SC, zero outside; valid s in [0,1026].
__global__ __launch_bounds__(64) void k_filter_pair(const float* __restrict__ x,
                                                    const float* __restrict__ cg,
                                                    float2* __restrict__ pair) {
    __shared__ float xsp[3264];
    int t = threadIdx.x;
    int col = blockIdx.x;
    float acc[16];
    filter_core(x, cg, xsp, t, col, acc);

    const float SC = (float)(PI_D / 360.0);
    float yv[16];
    #pragma unroll
    for (int m = 0; m < 16; ++m) yv[m] = acc[m] * SC;
    float ynext = __shfl_down(yv[0], 1);
    if (t == 63) ynext = 0.f;

    float2* rowp = pair + (size_t)col * RSP;
    int s0 = 16 * t + 2;
    #pragma unroll
    for (int m = 0; m < 15; ++m) rowp[s0 + m] = make_float2(yv[m], yv[m + 1]);
    rowp[s0 + 15] = make_float2(yv[15], ynext);
    if (t == 0) {
        rowp[0] = make_float2(0.f, 0.f);
        rowp[1] = make_float2(0.f, yv[0]);
    }
    if (t == 63) rowp[1026] = make_float2(0.f, 0.f);
}

// ---------------- LDS-staged backprojection ----------------
// 32x32 px tile per block, 256 threads, 4 y-px/thread (y = y0+ty+8k).
// Angles processed in 4 groups of 45; per group, 48-entry float2 windows per
// angle staged into LDS with coalesced loads, then taps read via ds_read_b64.
__global__ __launch_bounds__(256, 4) void k_bproj_lds(const float* __restrict__ ws,
                                                      const float2* __restrict__ pair,
                                                      float* __restrict__ out) {
    __shared__ float2 win[GANG * WIN];   // 17280 B
    __shared__ int   baseL[GANG];
    __shared__ float bfL[GANG];

    const float4* cst = (const float4*)(ws + OFF_CST);
    int t = threadIdx.x;
    int n = blockIdx.x;
    // XCD-batch swizzle: blocks ≡ i (mod 8) handle batches {i, i+8} -> per-XCD
    // pair working set ~3 MB -> L2-resident (R5: FETCH 89->11.7 MB).
    int b    = (n & 7) + 8 * ((n >> 3) & 1);
    int tile = n >> 4;                  // [0,1024)
    int bx = tile & 31;                 // x-tile (32 px)
    int by = tile >> 5;                 // y-tile (32 px)
    int tx = t & 31;
    int ty = t >> 5;                    // [0,8)
    int xg = bx * 32 + tx;
    int y0 = by * 32;
    int yg = y0 + ty;                   // pixel k at yg + 8k

    const float DEL = (float)(2.0 / 1023.0);
    // bit-exact jnp.linspace replication (mul then add, no contraction)
    float ux  = __fadd_rn(__fmul_rn((float)xg, DEL), -1.0f);
    float uy  = __fadd_rn(__fmul_rn((float)yg, DEL), -1.0f);
    float nuy = -uy;

    // tile-uniform corner coords
    float cxl = __fadd_rn(__fmul_rn((float)(bx*32),      DEL), -1.0f);
    float cxh = __fadd_rn(__fmul_rn((float)(bx*32 + 31), DEL), -1.0f);
    float cyl = __fadd_rn(__fmul_rn((float)(y0),         DEL), -1.0f);
    float cyh = __fadd_rn(__fmul_rn((float)(y0 + 31),    DEL), -1.0f);

    float minax = (cxl <= 0.f && cxh >= 0.f) ? 0.f : fminf(fabsf(cxl), fabsf(cxh));
    float minay = (cyl <= 0.f && cyh >= 0.f) ? 0.f : fminf(fabsf(cyl), fabsf(cyh));
    float rmin2 = minax * minax + minay * minay;
    float maxax = fmaxf(fabsf(cxl), fabsf(cxh));
    float maxay = fmaxf(fabsf(cyl), fabsf(cyh));
    float rmax2 = maxax * maxax + maxay * maxay;

    size_t o0 = ((size_t)b << 20) + ((size_t)yg << 10) + (size_t)xg;
    float* p0 = out + o0;

    if (rmin2 > 1.000001f) {            // tile fully outside: zeros, no barriers hit
        p0[0] = 0.f; p0[8 << 10] = 0.f; p0[16 << 10] = 0.f; p0[24 << 10] = 0.f;
        return;
    }

    bool interior = (rmax2 <= 0.9999f);
    const float2* slab = pair + (size_t)b * (AA * RSP);
    float a0 = 0.f, a1 = 0.f, a2 = 0.f, a3 = 0.f;
    float nyl = -cyl, nyh = -cyh;

    for (int g0 = 0; g0 < AA; g0 += GANG) {
        // --- per-angle window bases (tile-uniform) ---
        if (t < GANG) {
            float4 cs = cst[g0 + t];    // vector load (t varies)
            float mpx = fminf(cxl * cs.x, cxh * cs.x);
            float mpy = fminf(nyl * cs.y, nyh * cs.y);
            float minP = mpx + mpy + 513.5f;
            int base = (int)floorf(minP) - 1;
            base = min(max(base, 0), 1027 - WIN);
            baseL[t] = base;
            bfL[t] = 513.5f - (float)base;   // exact int subtraction
        }
        __syncthreads();

        // --- coalesced staging: 45 angles x 48 float2 ---
        for (int idx = t; idx < GANG * WIN; idx += 256) {
            int al = idx / WIN;
            int w  = idx - WIN * al;
            const float2* rp = slab + (size_t)(g0 + al) * RSP;
            win[idx] = rp[baseL[al] + w];
        }
        __syncthreads();

        // --- compute 45 angles from LDS ---
        if (interior) {
            #pragma unroll 3
            for (int g = 0; g < GANG; ++g) {
                float4 cs = cst[g0 + g];        // uniform -> s_load_dwordx4
                float bf = bfL[g];              // broadcast ds_read
                float P0 = fmaf(ux, cs.x, fmaf(nuy, cs.y, bf));
                float P1 = P0 + cs.z;
                float P2 = fmaf(2.0f, cs.z, P0);
                float P3 = P2 + cs.z;
                int j0 = (int)P0, j1 = (int)P1, j2 = (int)P2, j3 = (int)P3;
                const float2* wg = win + g * WIN;
                float2 d0 = wg[j0];
                float2 d1 = wg[j1];
                float2 d2 = wg[j2];
                float2 d3 = wg[j3];
                float f0 = fractf_(P0), f1 = fractf_(P1), f2v = fractf_(P2), f3 = fractf_(P3);
                a0 = fmaf(f0, d0.y - d0.x, a0 + d0.x);
                a1 = fmaf(f1, d1.y - d1.x, a1 + d1.x);
                a2 = fmaf(f2v, d2.y - d2.x, a2 + d2.x);
                a3 = fmaf(f3, d3.y - d3.x, a3 + d3.x);
            }
        } else {
            #pragma unroll 3
            for (int g = 0; g < GANG; ++g) {
                float4 cs = cst[g0 + g];
                float bf = bfL[g];
                float P0 = fmaf(ux, cs.x, fmaf(nuy, cs.y, bf));
                float P1 = P0 + cs.z;
                float P2 = fmaf(2.0f, cs.z, P0);
                float P3 = P2 + cs.z;
                int j0 = (int)P0, j1 = (int)P1, j2 = (int)P2, j3 = (int)P3;
                j0 = min(max(j0, 0), WIN - 1); j1 = min(max(j1, 0), WIN - 1);
                j2 = min(max(j2, 0), WIN - 1); j3 = min(max(j3, 0), WIN - 1);
                const float2* wg = win + g * WIN;
                float2 d0 = wg[j0];
                float2 d1 = wg[j1];
                float2 d2 = wg[j2];
                float2 d3 = wg[j3];
                float f0 = fractf_(P0), f1 = fractf_(P1), f2v = fractf_(P2), f3 = fractf_(P3);
                a0 = fmaf(f0, d0.y - d0.x, a0 + d0.x);
                a1 = fmaf(f1, d1.y - d1.x, a1 + d1.x);
                a2 = fmaf(f2v, d2.y - d2.x, a2 + d2.x);
                a3 = fmaf(f3, d3.y - d3.x, a3 + d3.x);
            }
        }
        __syncthreads();   // protect baseL/win before next group
    }

    if (interior) {
        p0[0] = a0; p0[8 << 10] = a1; p0[16 << 10] = a2; p0[24 << 10] = a3;
    } else {
        // bit-exact circle mask per pixel (in-circle px had exact j/fract; out px masked)
        float uy1 = __fadd_rn(__fmul_rn((float)(yg + 8),  DEL), -1.0f);
        float uy2 = __fadd_rn(__fmul_rn((float)(yg + 16), DEL), -1.0f);
        float uy3 = __fadd_rn(__fmul_rn((float)(yg + 24), DEL), -1.0f);
        float xx = __fmul_rn(ux, ux);
        float r20 = __fadd_rn(xx, __fmul_rn(uy,  uy));
        float r21 = __fadd_rn(xx, __fmul_rn(uy1, uy1));
        float r22 = __fadd_rn(xx, __fmul_rn(uy2, uy2));
        float r23 = __fadd_rn(xx, __fmul_rn(uy3, uy3));
        p0[0]        = (r20 <= 1.0f) ? a0 : 0.f;
        p0[8 << 10]  = (r21 <= 1.0f) ? a1 : 0.f;
        p0[16 << 10] = (r22 <= 1.0f) ? a2 : 0.f;
        p0[24 << 10] = (r23 <= 1.0f) ? a3 : 0.f;
    }
}

// ================= fallback path (R3, proven) — used if ws too small ==========
__global__ __launch_bounds__(64) void k_filter_sc(const float* __restrict__ x,
                                                  const float* __restrict__ cg,
                                                  float* __restrict__ xaf) {
    __shared__ float xsp[3264];
    int t = threadIdx.x;
    int col = blockIdx.x;
    float acc[16];
    filter_core(x, cg, xsp, t, col, acc);

    const float SC = (float)(PI_D / 360.0);
    float* rb = xaf + (size_t)col * RS;
    if (t < 12)            ((float4*)rb)[t]              = make_float4(0.f,0.f,0.f,0.f);
    else if (t < 24)       ((float4*)rb)[268 + (t - 12)] = make_float4(0.f,0.f,0.f,0.f);
    float4* o4 = (float4*)(rb + GUARD + 16 * t);
    #pragma unroll
    for (int m4 = 0; m4 < 4; ++m4)
        o4[m4] = make_float4(acc[4*m4]*SC, acc[4*m4+1]*SC, acc[4*m4+2]*SC, acc[4*m4+3]*SC);
}

__global__ __launch_bounds__(256, 4) void k_bproj_sc(const float* __restrict__ ws,
                                                     const float* __restrict__ xaf,
                                                     float* __restrict__ out) {
    const float2* cst2 = (const float2*)(ws + OFF_CST2);
    int t = threadIdx.x;
    int tx = t & 15, ty = t >> 4;
    int bx = blockIdx.x, by = blockIdx.y, b = blockIdx.z;
    int xg = bx * 16 + tx, yg = by * 16 + ty;
    const float DEL = (float)(2.0 / 1023.0);
    float ux = __fadd_rn(__fmul_rn((float)xg, DEL), -1.0f);
    float uy = __fadd_rn(__fmul_rn((float)yg, DEL), -1.0f);

    float cx0 = __fadd_rn(__fmul_rn((float)(bx*16),      DEL), -1.0f);
    float cx1 = __fadd_rn(__fmul_rn((float)(bx*16 + 15), DEL), -1.0f);
    float cy0 = __fadd_rn(__fmul_rn((float)(by*16),      DEL), -1.0f);
    float cy1 = __fadd_rn(__fmul_rn((float)(by*16 + 15), DEL), -1.0f);
    float minax = (cx0 <= 0.f && cx1 >= 0.f) ? 0.f : fminf(fabsf(cx0), fabsf(cx1));
    float minay = (cy0 <= 0.f && cy1 >= 0.f) ? 0.f : fminf(fabsf(cy0), fabsf(cy1));
    float rmin2 = minax * minax + minay * minay;

    size_t oidx = ((size_t)b << 20) + ((size_t)yg << 10) + (size_t)xg;
    if (rmin2 > 1.000001f) { out[oidx] = 0.f; return; }

    const float* row = xaf + (size_t)b * (AA * RS);
    const float BIAS = 511.5f + (float)GUARD;
    float nuy = -uy;
    float acc = 0.f;

    #pragma unroll 4
    for (int a = 0; a < AA; ++a) {
        float2 cs = cst2[a];
        float iy = fmaf(ux, cs.x, fmaf(nuy, cs.y, BIAS));
        int j = (int)iy;
        float fy = fractf_(iy);
        float v0 = row[j];
        float v1 = row[j + 1];
        acc = fmaf(fy, v1 - v0, acc + v0);
        row += RS;
    }

    float r2 = __fadd_rn(__fmul_rn(ux, ux), __fmul_rn(uy, uy));
    out[oidx] = (r2 <= 1.0f) ? acc : 0.f;
}

extern "C" void kernel_launch(void* const* d_in, const int* in_sizes, int n_in,
                              void* d_out, int out_size, void* d_ws, size_t ws_size,
                              hipStream_t stream) {
    const float* x = (const float*)d_in[0];
    float* out = (float*)d_out;
    float* ws = (float*)d_ws;
    float* cg  = ws + OFF_CG;

    hipLaunchKernelGGL(k_tables, dim3(1), dim3(512), 0, stream, ws);

    size_t need_pair = (size_t)OFF_DATA * 4 + (size_t)NCOL * RSP * sizeof(float2);
    if (ws_size >= need_pair) {
        float2* pair = (float2*)(ws + OFF_DATA);
        hipLaunchKernelGGL(k_filter_pair, dim3(NCOL), dim3(64), 0, stream, x, cg, pair);
        hipLaunchKernelGGL(k_bproj_lds, dim3(16384), dim3(256), 0, stream, ws, pair, out);
    } else {
        float* xaf = ws + OFF_DATA;
        hipLaunchKernelGGL(k_filter_sc, dim3(NCOL), dim3(64), 0, stream, x, cg, xaf);
        hipLaunchKernelGGL(k_bproj_sc, dim3(64, 64, BB), dim3(256), 0, stream, ws, xaf, out);
    }
}